// Round 12
// baseline (164.538 us; speedup 1.0000x reference)
//
#include <hip/hip_runtime.h>

// Problem constants (fixed by setup_inputs)
constexpr int B  = 2, T = 2, C = 6, Cr = 64, Hp = 32, Wp = 88;
constexpr int H  = 256, W = 704;
constexpr int HB = 200, WB = 200;
constexpr int NB   = B * T * C;       // 24 camera-slices
constexpr int BT   = B * T;           // 4
constexpr int P    = Hp * Wp;         // 2816 points per slice
constexpr int NBIN = HB * WB;         // 40000 bins
constexpr int PTS_BT = C * P;         // 16896 points per (b,t)

constexpr float X_MIN = -50.f, Y_MIN = -50.f;

// CSR bucketing: 64-bin tiles (625 divides NBIN exactly)
constexpr int TB     = 64;
constexpr int TILES  = NBIN / TB;     // 625
constexpr int NBUCK  = BT * TILES;    // 2500

// workspace layout (bytes, in order):
// cnt [NB*NBIN] | tilecnt [NBUCK] | off [NBUCK] | cursor [NBUCK] |
// binidx [NB*P] | rec [NB*P] | feats_t [NB*P*Cr]
constexpr size_t CNT_BYTES   = (size_t)NB * NBIN * 4;   // 3,840,000
constexpr size_t TCNT_BYTES  = (size_t)NBUCK * 4;       //    10,000
constexpr size_t OFF_BYTES   = (size_t)NBUCK * 4;
constexpr size_t CUR_BYTES   = (size_t)NBUCK * 4;
constexpr size_t BIDX_BYTES  = (size_t)NB * P * 4;      //   270,336
constexpr size_t REC_BYTES   = (size_t)NB * P * 4;

// ---------------------------------------------------------------------------
// Phase A: geometry -> binidx (or -1), per-camera cnt, per-bucket tilecnt
// grid = (P/256 = 11, NB), block = 256
// ---------------------------------------------------------------------------
__global__ void geom_kernel(const float* __restrict__ depths,
                            const float* __restrict__ Kmat,
                            const float* __restrict__ Tmat,
                            int* __restrict__ binidx,
                            int* __restrict__ cnt,
                            int* __restrict__ tilecnt) {
    const int n = blockIdx.y;
    const int p = blockIdx.x * blockDim.x + threadIdx.x;
    const int v = p / Wp, u = p % Wp;

    const float* Kp = Kmat + n * 9;
    const float* M  = Tmat + n * 16;

    const float Sx = (float)Wp / (float)W;  // 0.125
    const float Sy = (float)Hp / (float)H;  // 0.125
    const float fx = Kp[0] * Sx, cx = Kp[2] * Sx;
    const float fy = Kp[4] * Sy, cy = Kp[5] * Sy;

    // rigid inverse: inv = [R^T | -R^T t], need rows 0,1
    const float r00 = M[0], t0 = M[3];
    const float r10 = M[4], t1 = M[7];
    const float r20 = M[8], t2 = M[11];
    const float r01 = M[1], r11 = M[5], r21 = M[9];
    const float ti0 = -(r00 * t0 + r10 * t1 + r20 * t2);
    const float ti1 = -(r01 * t0 + r11 * t1 + r21 * t2);

    const float d = depths[(size_t)n * H * W + (size_t)(v * (H / Hp)) * W + u * (W / Wp)];

    const float xc = ((float)u - cx) / fx * d;
    const float yc = ((float)v - cy) / fy * d;
    const float x  = r00 * xc + r10 * yc + r20 * d + ti0;
    const float y  = r01 * xc + r11 * yc + r21 * d + ti1;

    const bool valid = (d > 0.f) && (x >= X_MIN) && (x < -X_MIN) &&
                       (y >= Y_MIN) && (y < -Y_MIN);
    int bin = -1;
    if (valid) {
        const float ixf = floorf((x - X_MIN) * 2.f);
        const float iyf = floorf((y - Y_MIN) * 2.f);
        const int ix = (int)fminf(fmaxf(ixf, 0.f), (float)(WB - 1));
        const int iy = (int)fminf(fmaxf(iyf, 0.f), (float)(HB - 1));
        bin = iy * WB + ix;
        atomicAdd(&cnt[n * NBIN + bin], 1);
        atomicAdd(&tilecnt[(n / C) * TILES + (bin >> 6)], 1);
    }
    binidx[n * P + p] = bin;
}

// ---------------------------------------------------------------------------
// Phase B: exclusive scan over 2500 bucket counts -> off, cursor
// grid = 1 block, 256 threads, 10 elements/thread
// ---------------------------------------------------------------------------
__global__ void scan_kernel(const int* __restrict__ tilecnt,
                            int* __restrict__ off,
                            int* __restrict__ cursor) {
    __shared__ int part[256];
    const int t = threadIdx.x;
    constexpr int CH = (NBUCK + 255) / 256;   // 10
    int pre[CH];
    int s = 0;
#pragma unroll
    for (int k = 0; k < CH; ++k) {
        const int i = t * CH + k;
        pre[k] = s;
        if (i < NBUCK) s += tilecnt[i];
    }
    part[t] = s;
    __syncthreads();
    // Hillis-Steele inclusive scan of per-thread sums
    for (int dlt = 1; dlt < 256; dlt <<= 1) {
        const int v = (t >= dlt) ? part[t - dlt] : 0;
        __syncthreads();
        part[t] += v;
        __syncthreads();
    }
    const int excl = (t == 0) ? 0 : part[t - 1];
#pragma unroll
    for (int k = 0; k < CH; ++k) {
        const int i = t * CH + k;
        if (i < NBUCK) {
            const int o = excl + pre[k];
            off[i] = o;
            cursor[i] = o;
        }
    }
}

// ---------------------------------------------------------------------------
// Phase C: fill packed records rec[pos] = (p_bt << 6) | (bin & 63)
// grid = (P/256 = 11, NB), block = 256
// ---------------------------------------------------------------------------
__global__ void fill_kernel(const int* __restrict__ binidx,
                            int* __restrict__ cursor,
                            int* __restrict__ rec) {
    const int n = blockIdx.y;
    const int p = blockIdx.x * blockDim.x + threadIdx.x;
    const int b = binidx[n * P + p];
    if (b >= 0) {
        const int bt  = n / C;
        const int pbt = (n % C) * P + p;               // point idx within bt
        const int pos = atomicAdd(&cursor[bt * TILES + (b >> 6)], 1);
        rec[pos] = (pbt << 6) | (b & 63);
    }
}

// ---------------------------------------------------------------------------
// Phase D: transpose feats [n][cr][p] -> feats_t [n][p][cr]
// grid = (P/64 = 44, NB), block = 256; 64x64 tile in LDS (padded)
// ---------------------------------------------------------------------------
__global__ void transpose_kernel(const float* __restrict__ feats,
                                 float* __restrict__ feats_t) {
    __shared__ float tile[64][65];
    const int n  = blockIdx.y;
    const int p0 = blockIdx.x * 64;
    const int tp = threadIdx.x & 63;
    const int tq = threadIdx.x >> 6;

    const float* src = feats + (size_t)n * Cr * P + p0;   // [cr][p]
#pragma unroll
    for (int k = 0; k < 16; ++k) {
        const int cr = k * 4 + tq;
        tile[cr][tp] = src[(size_t)cr * P + tp];          // coalesced 256B
    }
    __syncthreads();
    float* dst = feats_t + ((size_t)n * P + p0) * Cr;     // [p][cr]
#pragma unroll
    for (int k = 0; k < 16; ++k) {
        const int p = k * 4 + tq;
        dst[(size_t)p * Cr + tp] = tile[tp][p];           // coalesced 256B
    }
}

// ---------------------------------------------------------------------------
// Phase E: CSR-driven LDS accumulation + fused den/finalize.
// One block per (tile, bt). acc[64][64] f32 (16KB LDS), XOR-swizzled:
//   slot(bl,cr) = bl*64 + (cr ^ (bl & 31))   -> 2-way on both paths (free)
// Each wave takes one record per iteration (stride 4): broadcast rec read,
// coalesced 256B feats_t read (lane = cr), conflict-free LDS atomicAdd.
// Iterations independent -> ILP. Work proportional to bucket size only.
// Epilogue: den = sum_c max(cnt,1) read from L2; coalesced out stores.
// grid = (TILES = 625, BT = 4), block = 256
// ---------------------------------------------------------------------------
__global__ void accum_kernel(const float* __restrict__ feats_t,
                             const int* __restrict__ rec,
                             const int* __restrict__ off,
                             const int* __restrict__ cursor,
                             const int* __restrict__ cnt,
                             float* __restrict__ out) {
    __shared__ float acc[TB * 64];
    const int bt   = blockIdx.y;
    const int tile = blockIdx.x;
    const int lo   = tile * TB;

    for (int i = threadIdx.x; i < TB * 64; i += 256) acc[i] = 0.f;
    __syncthreads();

    const int lane = threadIdx.x & 63;
    const int wave = threadIdx.x >> 6;
    const int bucket = bt * TILES + tile;
    const int start = off[bucket];
    const int end   = cursor[bucket];     // = start + count (post-fill)
    const float* f  = feats_t + (size_t)bt * PTS_BT * Cr;

    for (int j = start + wave; j < end; j += 4) {
        const int r  = rec[j];            // wave-uniform broadcast load
        const int bl = r & 63;
        const int p  = r >> 6;
        const float v = f[(size_t)p * Cr + lane];          // coalesced 256B
        atomicAdd(&acc[bl * 64 + (lane ^ (bl & 31))], v);
    }
    __syncthreads();

    // epilogue: lane = bin_local, wave owns 16 channels
    const int bin = lo + lane;
    float den = 0.f;
#pragma unroll
    for (int c = 0; c < C; ++c) {
        const int cc = cnt[(bt * C + c) * NBIN + bin];
        den += (float)(cc > 1 ? cc : 1);
    }
    const float rden = 1.f / den;
    float* ob = out + (size_t)bt * Cr * NBIN + bin;
#pragma unroll
    for (int k = 0; k < 16; ++k) {
        const int cr = wave * 16 + k;
        ob[(size_t)cr * NBIN] = acc[lane * 64 + (cr ^ (lane & 31))] * rden;
    }
}

extern "C" void kernel_launch(void* const* d_in, const int* in_sizes, int n_in,
                              void* d_out, int out_size, void* d_ws, size_t ws_size,
                              hipStream_t stream) {
    const float* feats  = (const float*)d_in[0];
    const float* depths = (const float*)d_in[1];
    const float* Kmat   = (const float*)d_in[2];
    const float* Tmat   = (const float*)d_in[3];

    char* w = (char*)d_ws;
    int*   cnt     = (int*)w;                      w += CNT_BYTES;
    int*   tilecnt = (int*)w;                      w += TCNT_BYTES;
    int*   off     = (int*)w;                      w += OFF_BYTES;
    int*   cursor  = (int*)w;                      w += CUR_BYTES;
    int*   binidx  = (int*)w;                      w += BIDX_BYTES;
    int*   rec     = (int*)w;                      w += REC_BYTES;
    float* feats_t = (float*)w;
    float* out     = (float*)d_out;

    // zero cnt + tilecnt (contiguous)
    hipMemsetAsync(cnt, 0, CNT_BYTES + TCNT_BYTES, stream);

    geom_kernel<<<dim3(P / 256, NB), 256, 0, stream>>>(depths, Kmat, Tmat,
                                                       binidx, cnt, tilecnt);
    scan_kernel<<<1, 256, 0, stream>>>(tilecnt, off, cursor);
    fill_kernel<<<dim3(P / 256, NB), 256, 0, stream>>>(binidx, cursor, rec);
    transpose_kernel<<<dim3(P / 64, NB), 256, 0, stream>>>(feats, feats_t);
    accum_kernel<<<dim3(TILES, BT), 256, 0, stream>>>(feats_t, rec, off,
                                                      cursor, cnt, out);
}

// Round 14
// 162.096 us; speedup vs baseline: 1.0151x; 1.0151x over previous
//
#include <hip/hip_runtime.h>

// Problem constants (fixed by setup_inputs)
constexpr int B  = 2, T = 2, C = 6, Cr = 64, Hp = 32, Wp = 88;
constexpr int H  = 256, W = 704;
constexpr int HB = 200, WB = 200;
constexpr int NB   = B * T * C;       // 24 camera-slices
constexpr int BT   = B * T;           // 4
constexpr int P    = Hp * Wp;         // 2816 points per slice
constexpr int NBIN = HB * WB;         // 40000 bins
constexpr int NPTS = NB * P;          // 67584

constexpr float X_MIN = -50.f, Y_MIN = -50.f;

// CSR bucketing: 64-bin tiles (625 divides NBIN exactly)
constexpr int TB     = 64;
constexpr int TILES  = NBIN / TB;     // 625
constexpr int NBUCK  = BT * TILES;    // 2500

// workspace layout (in order):
// tilecnt [NBUCK] | off [NBUCK] | cursor [NBUCK] | binidx [NPTS] |
// meta [NPTS] | csr_feat [NPTS*Cr floats]
constexpr size_t TCNT_BYTES = (size_t)NBUCK * 4;
constexpr size_t OFF_BYTES  = (size_t)NBUCK * 4;
constexpr size_t CUR_BYTES  = (size_t)NBUCK * 4;
constexpr size_t BIDX_BYTES = (size_t)NPTS * 4;
constexpr size_t META_BYTES = (size_t)NPTS * 4;

// ---------------------------------------------------------------------------
// Phase A: geometry -> binidx (or -1), per-bucket tilecnt
// grid = (P/256 = 11, NB), block = 256
// ---------------------------------------------------------------------------
__global__ void geom_kernel(const float* __restrict__ depths,
                            const float* __restrict__ Kmat,
                            const float* __restrict__ Tmat,
                            int* __restrict__ binidx,
                            int* __restrict__ tilecnt) {
    const int n = blockIdx.y;
    const int p = blockIdx.x * blockDim.x + threadIdx.x;
    const int v = p / Wp, u = p % Wp;

    const float* Kp = Kmat + n * 9;
    const float* M  = Tmat + n * 16;

    const float Sx = (float)Wp / (float)W;  // 0.125
    const float Sy = (float)Hp / (float)H;  // 0.125
    const float fx = Kp[0] * Sx, cx = Kp[2] * Sx;
    const float fy = Kp[4] * Sy, cy = Kp[5] * Sy;

    // rigid inverse: inv = [R^T | -R^T t], need rows 0,1
    const float r00 = M[0], t0 = M[3];
    const float r10 = M[4], t1 = M[7];
    const float r20 = M[8], t2 = M[11];
    const float r01 = M[1], r11 = M[5], r21 = M[9];
    const float ti0 = -(r00 * t0 + r10 * t1 + r20 * t2);
    const float ti1 = -(r01 * t0 + r11 * t1 + r21 * t2);

    const float d = depths[(size_t)n * H * W + (size_t)(v * (H / Hp)) * W + u * (W / Wp)];

    const float xc = ((float)u - cx) / fx * d;
    const float yc = ((float)v - cy) / fy * d;
    const float x  = r00 * xc + r10 * yc + r20 * d + ti0;
    const float y  = r01 * xc + r11 * yc + r21 * d + ti1;

    const bool valid = (d > 0.f) && (x >= X_MIN) && (x < -X_MIN) &&
                       (y >= Y_MIN) && (y < -Y_MIN);
    int bin = -1;
    if (valid) {
        const float ixf = floorf((x - X_MIN) * 2.f);
        const float iyf = floorf((y - Y_MIN) * 2.f);
        const int ix = (int)fminf(fmaxf(ixf, 0.f), (float)(WB - 1));
        const int iy = (int)fminf(fmaxf(iyf, 0.f), (float)(HB - 1));
        bin = iy * WB + ix;
        atomicAdd(&tilecnt[(n / C) * TILES + (bin >> 6)], 1);
    }
    binidx[n * P + p] = bin;
}

// ---------------------------------------------------------------------------
// Phase B: exclusive scan over 2500 bucket counts -> off, cursor
// grid = 1 block, 256 threads
// ---------------------------------------------------------------------------
__global__ void scan_kernel(const int* __restrict__ tilecnt,
                            int* __restrict__ off,
                            int* __restrict__ cursor) {
    __shared__ int part[256];
    const int t = threadIdx.x;
    constexpr int CH = (NBUCK + 255) / 256;   // 10
    int pre[CH];
    int s = 0;
#pragma unroll
    for (int k = 0; k < CH; ++k) {
        const int i = t * CH + k;
        pre[k] = s;
        if (i < NBUCK) s += tilecnt[i];
    }
    part[t] = s;
    __syncthreads();
    for (int dlt = 1; dlt < 256; dlt <<= 1) {
        const int v = (t >= dlt) ? part[t - dlt] : 0;
        __syncthreads();
        part[t] += v;
        __syncthreads();
    }
    const int excl = (t == 0) ? 0 : part[t - 1];
#pragma unroll
    for (int k = 0; k < CH; ++k) {
        const int i = t * CH + k;
        if (i < NBUCK) {
            const int o = excl + pre[k];
            off[i] = o;
            cursor[i] = o;
        }
    }
}

// ---------------------------------------------------------------------------
// Phase C: fused transpose + CSR fill. Per block: 64 points of slice n.
// Wave 0 allocates CSR slots (atomic cursor) and writes meta = bl | c<<6;
// all waves LDS-transpose the 64x64 feats tile; then each point's 64-chan
// row is written contiguously to csr_feat[pos*64 + cr]  (coalesced 256B).
// grid = (P/64 = 44, NB), block = 256
// ---------------------------------------------------------------------------
__global__ void fillT_kernel(const float* __restrict__ feats,
                             const int* __restrict__ binidx,
                             int* __restrict__ cursor,
                             int* __restrict__ meta,
                             float* __restrict__ csr_feat) {
    __shared__ float tile[64][65];
    __shared__ int posArr[64];
    const int n    = blockIdx.y;
    const int p0   = blockIdx.x * 64;
    const int t    = threadIdx.x;
    const int lane = t & 63, wq = t >> 6;
    const int bt = n / C, c = n % C;

    if (t < 64) {                       // wave 0: slot allocation
        const int b = binidx[n * P + p0 + t];
        int pos = -1;
        if (b >= 0) {
            pos = atomicAdd(&cursor[bt * TILES + (b >> 6)], 1);
            meta[pos] = (b & 63) | (c << 6);
        }
        posArr[t] = pos;
    }
    const float* src = feats + (size_t)n * Cr * P + p0;   // [cr][p]
#pragma unroll
    for (int k = 0; k < 16; ++k) {
        const int cr = k * 4 + wq;
        tile[cr][lane] = src[(size_t)cr * P + lane];      // coalesced 256B
    }
    __syncthreads();
#pragma unroll
    for (int k = 0; k < 16; ++k) {
        const int pt  = wq * 16 + k;
        const int pos = posArr[pt];                       // wave-uniform
        if (pos >= 0)
            csr_feat[(size_t)pos * 64 + lane] = tile[lane][pt];  // coalesced
    }
}

// ---------------------------------------------------------------------------
// Phase D: CSR-streaming LDS accumulation + per-camera counts + finalize.
// One block per (tile, bt). acc[64][64] XOR-swizzled (conflict-free both
// paths); cntc[64][9] per-(bin,cam) counts -> den locally (no global cnt).
// Inner loop streams csr_feat contiguously: address = j*64+lane (no
// dependent gather) -> loads pipeline across iterations.
// grid = (TILES = 625, BT = 4), block = 256
// ---------------------------------------------------------------------------
__global__ void accum_kernel(const float* __restrict__ csr_feat,
                             const int* __restrict__ meta,
                             const int* __restrict__ off,
                             const int* __restrict__ cursor,
                             float* __restrict__ out) {
    __shared__ float acc[TB * 64];
    __shared__ int cntc[TB * 9];
    const int bt   = blockIdx.y;
    const int tile = blockIdx.x;
    const int lo   = tile * TB;

    for (int i = threadIdx.x; i < TB * 64; i += 256) acc[i] = 0.f;
    for (int i = threadIdx.x; i < TB * 9; i += 256) cntc[i] = 0;
    __syncthreads();

    const int lane = threadIdx.x & 63;
    const int wave = threadIdx.x >> 6;
    const int bucket = bt * TILES + tile;
    const int start = off[bucket];
    const int end   = cursor[bucket];         // = start + count

    for (int j = start + wave; j < end; j += 4) {
        const int m  = meta[j];               // wave-uniform
        const int bl = m & 63;
        const float v = csr_feat[(size_t)j * 64 + lane];   // streaming 256B
        atomicAdd(&acc[bl * 64 + (lane ^ (bl & 31))], v);
        if (lane == 0) atomicAdd(&cntc[bl * 9 + (m >> 6)], 1);
    }
    __syncthreads();

    // epilogue: lane = bin_local; each wave writes 16 channels
    const int bin = lo + lane;
    float den = 0.f;
#pragma unroll
    for (int c = 0; c < C; ++c) {
        const int cc = cntc[lane * 9 + c];
        den += (float)(cc > 1 ? cc : 1);
    }
    const float r = 1.f / den;
    float* ob = out + (size_t)bt * Cr * NBIN + bin;
#pragma unroll
    for (int k = 0; k < 16; ++k) {
        const int cr = wave * 16 + k;
        ob[(size_t)cr * NBIN] = acc[lane * 64 + (cr ^ (lane & 31))] * r;
    }
}

extern "C" void kernel_launch(void* const* d_in, const int* in_sizes, int n_in,
                              void* d_out, int out_size, void* d_ws, size_t ws_size,
                              hipStream_t stream) {
    const float* feats  = (const float*)d_in[0];
    const float* depths = (const float*)d_in[1];
    const float* Kmat   = (const float*)d_in[2];
    const float* Tmat   = (const float*)d_in[3];

    char* w = (char*)d_ws;
    int*   tilecnt  = (int*)w;   w += TCNT_BYTES;
    int*   off      = (int*)w;   w += OFF_BYTES;
    int*   cursor   = (int*)w;   w += CUR_BYTES;
    int*   binidx   = (int*)w;   w += BIDX_BYTES;
    int*   meta     = (int*)w;   w += META_BYTES;
    float* csr_feat = (float*)w;
    float* out      = (float*)d_out;

    hipMemsetAsync(tilecnt, 0, TCNT_BYTES, stream);   // 10 KB only

    geom_kernel<<<dim3(P / 256, NB), 256, 0, stream>>>(depths, Kmat, Tmat,
                                                       binidx, tilecnt);
    scan_kernel<<<1, 256, 0, stream>>>(tilecnt, off, cursor);
    fillT_kernel<<<dim3(P / 64, NB), 256, 0, stream>>>(feats, binidx, cursor,
                                                       meta, csr_feat);
    accum_kernel<<<dim3(TILES, BT), 256, 0, stream>>>(csr_feat, meta, off,
                                                      cursor, out);
}